// Round 5
// baseline (177.562 us; speedup 1.0000x reference)
//
#include <hip/hip_runtime.h>
#include <hip/hip_bf16.h>
#include <math.h>

#define EMBED 1024
#define HDIM  64
#define BATCH 4
#define SEQ   2048

typedef __attribute__((ext_vector_type(8))) short short8;
typedef __attribute__((ext_vector_type(4))) float f32x4;
typedef unsigned int u32;
typedef unsigned short u16;

static __device__ __forceinline__ u16 f2bf(float f) {
    union { float f; u32 u; } v; v.f = f;
    u32 r = v.u + 0x7fffu + ((v.u >> 16) & 1u);  // round-to-nearest-even
    return (u16)(r >> 16);
}

// async global->LDS, 16B per lane. LDS dest must equal uniform_base + lane*16.
static __device__ __forceinline__ void gload_lds16(const u16* g, u16* l) {
    __builtin_amdgcn_global_load_lds(
        (const __attribute__((address_space(1))) u32*)g,
        (__attribute__((address_space(3))) u32*)l, 16, 0, 0);
}

// ---------------------------------------------------------------------------
// K0: WqT[d][e] = bf16(Wq[e][d]), WkT likewise. grid (16,2) x 256.
// ---------------------------------------------------------------------------
__global__ __launch_bounds__(256) void wt_kernel(
    const float* __restrict__ Wq, const float* __restrict__ Wk,
    u16* __restrict__ WqT, u16* __restrict__ WkT)
{
    __shared__ float tile[64][65];
    const float* W = blockIdx.y ? Wk : Wq;
    u16* WT = blockIdx.y ? WkT : WqT;
    int e0 = blockIdx.x * 64;
    int t = threadIdx.x, c = t & 63, r4 = t >> 6;
    for (int r = r4; r < 64; r += 4)
        tile[r][c] = W[(size_t)(e0 + r) * HDIM + c];   // tile[e-e0][d]
    __syncthreads();
    for (int d = r4; d < 64; d += 4)
        WT[(size_t)d * EMBED + e0 + c] = f2bf(tile[c][d]);
}

// ---------------------------------------------------------------------------
// K1: proj only (transpose removed). Q = 0.125*(h*Wq+bq), K = h*Wk+bk.
// grid 512 (B * S/16), 256 thr, 16 s-rows/block, EC=128 per iter:
// 8 iters, 8 barriers, 8 MFMA + 4 ds_read_b128 per wave per iter.
// Double-buffered LDS; h prefetched DEPTH-2 (hides ~900cyc HBM latency),
// W-frags prefetched 1 iter ahead (L2-resident).
// ---------------------------------------------------------------------------
__global__ __launch_bounds__(256) void proj_kernel(
    const float* __restrict__ h, const u16* __restrict__ WqT, const u16* __restrict__ WkT,
    const float* __restrict__ bq, const float* __restrict__ bk,
    u16* __restrict__ Qbf, u16* __restrict__ Kbf)
{
    __shared__ u16 hs[2][16][136];   // 128 + 8 pad
    int b = blockIdx.x >> 7, s0 = (blockIdx.x & 127) * 16;
    int t = threadIdx.x, lane = t & 63, w = t >> 6;
    int l15 = lane & 15, quad = lane >> 4;
    int pj = w >> 1, nh = (w & 1) * 32;
    const float* hb = h + ((size_t)b * SEQ + s0) * EMBED;
    const u16* Wp = pj ? WkT : WqT;
    int r = t >> 4, c4 = (t & 15) * 4;   // staging: 16 rows x (16 f32x4 x 2 halves)

    f32x4 preA0 = *(const f32x4*)(hb + (size_t)r * EMBED + c4);
    f32x4 preA1 = *(const f32x4*)(hb + (size_t)r * EMBED + 64 + c4);
    f32x4 preB0 = *(const f32x4*)(hb + (size_t)r * EMBED + 128 + c4);
    f32x4 preB1 = *(const f32x4*)(hb + (size_t)r * EMBED + 192 + c4);
    f32x4 accA[2], accB[2];
    accA[0] = accA[1] = accB[0] = accB[1] = (f32x4){0.f, 0.f, 0.f, 0.f};

    const u16* Wrow0 = Wp + (size_t)(nh + l15) * EMBED;
    const u16* Wrow1 = Wp + (size_t)(nh + 16 + l15) * EMBED;

    short8 cw[8];
#pragma unroll
    for (int i = 0; i < 4; i++) {
        cw[i]     = *(const short8*)(Wrow0 + i * 32 + quad * 8);
        cw[4 + i] = *(const short8*)(Wrow1 + i * 32 + quad * 8);
    }

    for (int it = 0; it < 8; ++it) {
        int ec = it * 128, buf = it & 1;
        uint2 pk;
        pk.x = (u32)f2bf(preA0[0]) | ((u32)f2bf(preA0[1]) << 16);
        pk.y = (u32)f2bf(preA0[2]) | ((u32)f2bf(preA0[3]) << 16);
        *(uint2*)&hs[buf][r][c4] = pk;
        pk.x = (u32)f2bf(preA1[0]) | ((u32)f2bf(preA1[1]) << 16);
        pk.y = (u32)f2bf(preA1[2]) | ((u32)f2bf(preA1[3]) << 16);
        *(uint2*)&hs[buf][r][64 + c4] = pk;
        __syncthreads();

        preA0 = preB0; preA1 = preB1;
        if (it + 2 < 8) {
            preB0 = *(const f32x4*)(hb + (size_t)r * EMBED + ec + 256 + c4);
            preB1 = *(const f32x4*)(hb + (size_t)r * EMBED + ec + 320 + c4);
        }
        short8 nw[8];
#pragma unroll
        for (int i = 0; i < 8; i++) nw[i] = cw[i];
        if (it + 1 < 8) {
#pragma unroll
            for (int i = 0; i < 4; i++) {
                nw[i]     = *(const short8*)(Wrow0 + ec + 128 + i * 32 + quad * 8);
                nw[4 + i] = *(const short8*)(Wrow1 + ec + 128 + i * 32 + quad * 8);
            }
        }

        short8 a0 = *(const short8*)&hs[buf][l15][quad * 8];
        short8 a1 = *(const short8*)&hs[buf][l15][32 + quad * 8];
        short8 a2 = *(const short8*)&hs[buf][l15][64 + quad * 8];
        short8 a3 = *(const short8*)&hs[buf][l15][96 + quad * 8];
        // dependent accumulator reuses 4 apart
        accA[0] = __builtin_amdgcn_mfma_f32_16x16x32_bf16(a0, cw[0], accA[0], 0, 0, 0);
        accA[1] = __builtin_amdgcn_mfma_f32_16x16x32_bf16(a0, cw[4], accA[1], 0, 0, 0);
        accB[0] = __builtin_amdgcn_mfma_f32_16x16x32_bf16(a1, cw[1], accB[0], 0, 0, 0);
        accB[1] = __builtin_amdgcn_mfma_f32_16x16x32_bf16(a1, cw[5], accB[1], 0, 0, 0);
        accA[0] = __builtin_amdgcn_mfma_f32_16x16x32_bf16(a2, cw[2], accA[0], 0, 0, 0);
        accA[1] = __builtin_amdgcn_mfma_f32_16x16x32_bf16(a2, cw[6], accA[1], 0, 0, 0);
        accB[0] = __builtin_amdgcn_mfma_f32_16x16x32_bf16(a3, cw[3], accB[0], 0, 0, 0);
        accB[1] = __builtin_amdgcn_mfma_f32_16x16x32_bf16(a3, cw[7], accB[1], 0, 0, 0);
#pragma unroll
        for (int i = 0; i < 8; i++) cw[i] = nw[i];
    }

    const float* bias = pj ? bk : bq;
    float scale = pj ? 1.0f : 0.125f;
    u16* outp = pj ? Kbf : Qbf;
    float bv0 = bias[nh + l15], bv1 = bias[nh + 16 + l15];
#pragma unroll
    for (int rr = 0; rr < 4; rr++) {
        size_t row = (size_t)b * SEQ + s0 + quad * 4 + rr;
        outp[row * HDIM + nh + l15]      = f2bf((accA[0][rr] + accB[0][rr] + bv0) * scale);
        outp[row * HDIM + nh + 16 + l15] = f2bf((accA[1][rr] + accB[1][rr] + bv1) * scale);
    }
}

// ---------------------------------------------------------------------------
// K2 V2: coalesced-line sw. Block owns 64 CONTIGUOUS k (one full 128B line
// per q-row) x all q; 8 waves split q (256 q each). Old version's 16-wide
// k-slice meant each 128B Wmat line was written 16B at a time by 4 blocks
// on 4 DIFFERENT XCDs (false sharing, partial-sector writebacks). Now each
// q-row's 128B line is filled entirely by one wave in 4 adjacent stores.
// K-frags (64 rows x 64 d) loop-invariant in regs. Per 32-q iter:
// 16 MFMA (4 kgrp x 2 qgrp x 2 dhalf) -> 32 exp -> 8 packed uint2 stores
// + column-sum accumulation. l15-butterfly + LDS cross-wave reduce ->
// invl[k] = 1/sum_q exp(S[q,k]). grid (S/64, B) x 512.
// ---------------------------------------------------------------------------
__global__ __launch_bounds__(512) void sw_kernel(
    const u16* __restrict__ Qbf, const u16* __restrict__ Kbf,
    u16* __restrict__ Wmat, float* __restrict__ invl)
{
    __shared__ float sl[8][64];
    int b = blockIdx.y;
    int k0 = blockIdx.x * 64;
    int t = threadIdx.x, lane = t & 63, w = t >> 6;
    int l15 = lane & 15, quad = lane >> 4;
    const u16* Qb = Qbf + (size_t)b * SEQ * HDIM;
    const u16* Kb = Kbf + (size_t)b * SEQ * HDIM;
    u16* Wb = Wmat + (size_t)b * SEQ * SEQ;

    // K fragments: 4 k-16-groups x 2 d-halves, loop-invariant.
    short8 kfr[4][2];
#pragma unroll
    for (int g = 0; g < 4; g++)
#pragma unroll
        for (int hh = 0; hh < 2; hh++)
            kfr[g][hh] = *(const short8*)(
                Kb + (size_t)(k0 + g * 16 + l15) * HDIM + hh * 32 + quad * 8);

    f32x4 lacc[4];
#pragma unroll
    for (int g = 0; g < 4; g++) lacc[g] = (f32x4){0.f, 0.f, 0.f, 0.f};

    int qs = w * 256;
    short8 cf[2][2];
#pragma unroll
    for (int a = 0; a < 2; a++)
#pragma unroll
        for (int hh = 0; hh < 2; hh++)
            cf[a][hh] = *(const short8*)(
                Qb + (size_t)(qs + a * 16 + l15) * HDIM + hh * 32 + quad * 8);

    for (int q0 = qs; q0 < qs + 256; q0 += 32) {
        short8 nf[2][2];
#pragma unroll
        for (int a = 0; a < 2; a++)
#pragma unroll
            for (int hh = 0; hh < 2; hh++) nf[a][hh] = cf[a][hh];
        if (q0 + 32 < qs + 256) {
#pragma unroll
            for (int a = 0; a < 2; a++)
#pragma unroll
                for (int hh = 0; hh < 2; hh++)
                    nf[a][hh] = *(const short8*)(
                        Qb + (size_t)(q0 + 32 + a * 16 + l15) * HDIM + hh * 32 + quad * 8);
        }
        // A = K rows (m=k), B = Q rows (n=q):
        // acc[a][g][r] = S[q0 + a*16 + l15][k0 + g*16 + quad*4 + r]
        f32x4 acc[2][4];
#pragma unroll
        for (int a = 0; a < 2; a++)
#pragma unroll
            for (int g = 0; g < 4; g++) acc[a][g] = (f32x4){0.f, 0.f, 0.f, 0.f};
#pragma unroll
        for (int a = 0; a < 2; a++)
#pragma unroll
            for (int g = 0; g < 4; g++) {
                acc[a][g] = __builtin_amdgcn_mfma_f32_16x16x32_bf16(
                    kfr[g][0], cf[a][0], acc[a][g], 0, 0, 0);
                acc[a][g] = __builtin_amdgcn_mfma_f32_16x16x32_bf16(
                    kfr[g][1], cf[a][1], acc[a][g], 0, 0, 0);
            }
#pragma unroll
        for (int a = 0; a < 2; a++) {
            u16* wrow = Wb + (size_t)(q0 + a * 16 + l15) * SEQ + k0;
#pragma unroll
            for (int g = 0; g < 4; g++) {
                float e0 = __expf(acc[a][g][0]), e1 = __expf(acc[a][g][1]);
                float e2 = __expf(acc[a][g][2]), e3 = __expf(acc[a][g][3]);
                lacc[g][0] += e0; lacc[g][1] += e1;
                lacc[g][2] += e2; lacc[g][3] += e3;
                uint2 pk;
                pk.x = (u32)f2bf(e0) | ((u32)f2bf(e1) << 16);
                pk.y = (u32)f2bf(e2) | ((u32)f2bf(e3) << 16);
                *(uint2*)(wrow + g * 16 + quad * 4) = pk;
            }
        }
#pragma unroll
        for (int a = 0; a < 2; a++)
#pragma unroll
            for (int hh = 0; hh < 2; hh++) cf[a][hh] = nf[a][hh];
    }
    // sum over l15 (q within tile): butterfly over lane bits 0..3
#pragma unroll
    for (int m = 1; m <= 8; m <<= 1)
#pragma unroll
        for (int g = 0; g < 4; g++) {
            lacc[g][0] += __shfl_xor(lacc[g][0], m, 64);
            lacc[g][1] += __shfl_xor(lacc[g][1], m, 64);
            lacc[g][2] += __shfl_xor(lacc[g][2], m, 64);
            lacc[g][3] += __shfl_xor(lacc[g][3], m, 64);
        }
    if (l15 == 0) {
#pragma unroll
        for (int g = 0; g < 4; g++) {
            sl[w][g * 16 + quad * 4 + 0] = lacc[g][0];
            sl[w][g * 16 + quad * 4 + 1] = lacc[g][1];
            sl[w][g * 16 + quad * 4 + 2] = lacc[g][2];
            sl[w][g * 16 + quad * 4 + 3] = lacc[g][3];
        }
    }
    __syncthreads();
    if (t < 64) {
        float s = ((sl[0][t] + sl[1][t]) + (sl[2][t] + sl[3][t]))
                + ((sl[4][t] + sl[5][t]) + (sl[6][t] + sl[7][t]));
        invl[b * SEQ + k0 + t] = 1.0f / s;
    }
}

// ---------------------------------------------------------------------------
// K3: transpose + scale: hT[b][e][s] = bf16( h[b][s][e] * invl[b][s] ).
// 64x64 fp32 LDS tile, f32x4 global loads (coalesced), uint2 packed stores
// (4x fewer store instrs). grid (S/64, E/64, B) x 256.
// ---------------------------------------------------------------------------
__global__ __launch_bounds__(256) void tscale_kernel(
    const float* __restrict__ h, const float* __restrict__ invl,
    u16* __restrict__ hT)
{
    __shared__ float tile[64][65];
    int b  = blockIdx.z;
    int s0 = blockIdx.x * 64, e0 = blockIdx.y * 64;
    int t = threadIdx.x;
    int r16 = t >> 4, c4 = (t & 15) * 4;
    const float* hb = h + (size_t)b * SEQ * EMBED;
#pragma unroll
    for (int rr = r16; rr < 64; rr += 16) {
        f32x4 v = *(const f32x4*)(hb + (size_t)(s0 + rr) * EMBED + e0 + c4);
        *(f32x4*)&tile[rr][c4] = v;
    }
    __syncthreads();
    f32x4 il4 = *(const f32x4*)(invl + b * SEQ + s0 + c4);   // 4 s-columns
    u16* hTb = hT + (size_t)b * EMBED * SEQ;
#pragma unroll
    for (int er = r16; er < 64; er += 16) {
        u16 p0 = f2bf(tile[c4 + 0][er] * il4[0]);
        u16 p1 = f2bf(tile[c4 + 1][er] * il4[1]);
        u16 p2 = f2bf(tile[c4 + 2][er] * il4[2]);
        u16 p3 = f2bf(tile[c4 + 3][er] * il4[3]);
        uint2 pk;
        pk.x = (u32)p0 | ((u32)p1 << 16);
        pk.y = (u32)p2 | ((u32)p3 << 16);
        *(uint2*)(hTb + (size_t)(e0 + er) * SEQ + s0 + c4) = pk;
    }
}

// ---------------------------------------------------------------------------
// K4: out[b][q][e] = sum_k Wmat[b][q][k] * hT[b][e][k]
// V5 = R3's LOCKSTEP 2-phase schedule (best measured) + R4's hoisted
// loop-invariant addressing (low VALU). BM=256 x BN=128, BK=64, 512 thr =
// 8 waves (2 kf-groups x 2M x 2N; wave tile 128x64 over its 32-wide k-half;
// acc[8][4]). 3-slot LDS ring (144KB), depth-2 staging, counted vmcnt(6).
// Main loop unrolled x3 -> literal slot bases; LDS offsets hoisted;
// staging src pointers advance +64/tile. Per K-tile:
//  ph0: 12 ds_read + STAGE_H1 -> barrier -> lgkmcnt(0) -> setprio MFMA16(0)
//       -> barrier
//  ph1: 4 ds_read + STAGE_H2 -> barrier -> lgkmcnt(0) -> setprio MFMA16(4)
//       -> vmcnt(6) -> barrier   (vmcnt never 0 until kt=30)
// R4 lesson: free-running waves regressed (27.4% MfmaUtil vs 30.8) -- the
// lockstep barriers stagger waves so MFMA covers reads; keep them.
// Swizzle: phys chunk = logical ^ (row&7) on global source + ds_read side.
// Epilogue: kf=1 waves dump acc into retired ring LDS; kf=0 add + store.
// grid (8,8,4) = 256 blocks = 1/CU.
// ---------------------------------------------------------------------------
__global__ __launch_bounds__(512, 2) void out_gemm_kernel(
    const u16* __restrict__ Wmat, const u16* __restrict__ hT, float* __restrict__ out)
{
    __shared__ __align__(16) char smem[3 * 49152];   // 3 x (A 32KB + B 16KB)
    int b = blockIdx.z;
    int q0 = blockIdx.x * 256, e0 = blockIdx.y * 128;
    int t = threadIdx.x, lane = t & 63, w = t >> 6;
    int l15 = lane & 15, quad = lane >> 4;
    const u16* Wb  = Wmat + (size_t)b * SEQ * SEQ;
    const u16* hTb = hT + (size_t)b * EMBED * SEQ;
    int kf = w >> 2;                 // k-half group (0: k 0..31, 1: k 32..63)
    int wm = (w >> 1) & 1, wn = w & 1;
    int wq = wm * 128, we = wn * 64; // wave tile origin (128 x 64)

    f32x4 acc[8][4];
#pragma unroll
    for (int i = 0; i < 8; i++)
#pragma unroll
        for (int j = 0; j < 4; j++) acc[i][j] = (f32x4){0.f, 0.f, 0.f, 0.f};

    int st_rl = lane >> 3;            // row within 8-row group
    int st_pc = lane & 7;             // physical chunk at dest (= lane pattern)

    // ---- loop-invariant staging sources (advance +64 u16 per staged tile)
    const u16* gA[4];
    const u16* gB[2];
#pragma unroll
    for (int ld = 0; ld < 4; ld++) {
        int row = w * 32 + ld * 8 + st_rl;
        int cg  = st_pc ^ (row & 7);
        gA[ld] = Wb + (size_t)(q0 + row) * SEQ + cg * 8;
    }
#pragma unroll
    for (int ld = 0; ld < 2; ld++) {
        int row = w * 16 + ld * 8 + st_rl;
        int cg  = st_pc ^ (row & 7);
        gB[ld] = hTb + (size_t)(e0 + row) * SEQ + cg * 8;
    }
    // ---- loop-invariant LDS dest byte offsets within a slot
    int dA[4], dB[2];
#pragma unroll
    for (int ld = 0; ld < 4; ld++) dA[ld] = (w * 32 + ld * 8) * 128 + lane * 16;
#pragma unroll
    for (int ld = 0; ld < 2; ld++) dB[ld] = 32768 + (w * 16 + ld * 8) * 128 + lane * 16;
    // ---- loop-invariant LDS read byte offsets within a slot
    int offA[8], offB[4];
#pragma unroll
    for (int ii = 0; ii < 8; ii++) {
        int ra  = wq + ii * 16 + l15;
        int pca = (kf * 4 + quad) ^ (ra & 7);
        offA[ii] = ra * 128 + pca * 16;
    }
#pragma unroll
    for (int j = 0; j < 4; j++) {
        int rb  = we + j * 16 + l15;
        int pcb = (kf * 4 + quad) ^ (rb & 7);
        offB[j] = 32768 + rb * 128 + pcb * 16;
    }

#define STAGE_H1(si)                                                           \
    {                                                                          \
        gload_lds16(gA[0], (u16*)(smem + (si) * 49152 + dA[0]));               \
        gload_lds16(gA[1], (u16*)(smem + (si) * 49152 + dA[1]));               \
        gload_lds16(gB[0], (u16*)(smem + (si) * 49152 + dB[0]));               \
    }
#define STAGE_H2(si)                                                           \
    {                                                                          \
        gload_lds16(gA[2], (u16*)(smem + (si) * 49152 + dA[2]));               \
        gload_lds16(gA[3], (u16*)(smem + (si) * 49152 + dA[3]));               \
        gload_lds16(gB[1], (u16*)(smem + (si) * 49152 + dB[1]));               \
    }
#define ADV()                                                                  \
    {                                                                          \
        gA[0] += 64; gA[1] += 64; gA[2] += 64; gA[3] += 64;                    \
        gB[0] += 64; gB[1] += 64;                                              \
    }

#define MFMA16(i0)                                                             \
    {                                                                          \
        _Pragma("unroll")                                                      \
        for (int ii = 0; ii < 4; ii++)                                         \
            _Pragma("unroll")                                                  \
            for (int j = 0; j < 4; j++)                                        \
                acc[(i0) + ii][j] = __builtin_amdgcn_mfma_f32_16x16x32_bf16(   \
                    af[ii], bfr[j], acc[(i0) + ii][j], 0, 0, 0);               \
    }

    // TILE body: lockstep 2-phase, slot si (literal), staging into si2.
#define TILE(si, si2, DO_STAGE, VMC)                                           \
    {                                                                          \
        const char* Sb = smem + (si) * 49152;                                  \
        short8 af[4], bfr[4];                                                  \
        /* phase 0 */                                                          \
        _Pragma("unroll")                                                      \
        for (int ii = 0; ii < 4; ii++)                                         \
            af[ii] = *(const short8*)(Sb + offA[ii]);                          \
        _Pragma("unroll")                                                      \
        for (int j = 0; j < 4; j++)                                            \
            bfr[j] = *(const short8*)(Sb + offB[j]);                           \
        if (DO_STAGE) STAGE_H1(si2)                                            \
        __builtin_amdgcn_s_barrier();                                          \
        asm volatile("s_waitcnt lgkmcnt(0)" ::: "memory");                     \
        __builtin_amdgcn_sched_barrier(0);                                     \
        __builtin_amdgcn_s_setprio(1);                                         \
        MFMA16(0)                                                              \
        __builtin_amdgcn_s_setprio(0);                                         \
        __builtin_amdgcn_s_barrier();                                          \
        /* phase 1 */                                                          \
        _Pragma("unroll")                                                      \
        for (int ii = 0; ii < 4; ii++)                                         \
            af[ii] = *(const short8*)(Sb + offA[4 + ii]);                      \
        if (DO_STAGE) { STAGE_H2(si2) ADV() }                                  \
        __builtin_amdgcn_s_barrier();                                          \
        asm volatile("s_waitcnt lgkmcnt(0)" ::: "memory");                     \
        __builtin_amdgcn_sched_barrier(0);                                     \
        __builtin_amdgcn_s_setprio(1);                                         \
        MFMA16(4)                                                              \
        __builtin_amdgcn_s_setprio(0);                                         \
        if ((VMC) == 6) { asm volatile("s_waitcnt vmcnt(6)" ::: "memory"); }   \
        else if ((VMC) == 0) { asm volatile("s_waitcnt vmcnt(0)" ::: "memory"); } \
        __builtin_amdgcn_s_barrier();                                          \
    }

    // Prologue: stage tiles 0 (slot 0) and 1 (slot 1).
    STAGE_H1(0) STAGE_H2(0) ADV()
    STAGE_H1(1) STAGE_H2(1) ADV()
    asm volatile("s_waitcnt vmcnt(6)" ::: "memory");   // own tile-0 loads done
    __builtin_amdgcn_s_barrier();                      // published to all

    // Tiles 0..29: unrolled x3, staging tiles 2..31, vmcnt(6) each.
    for (int g = 0; g < 10; ++g) {
        TILE(0, 2, true, 6)
        TILE(1, 0, true, 6)
        TILE(2, 1, true, 6)
    }
    // Tile 30 (slot 0): no staging; drain remaining (tile 31's 6 loads).
    TILE(0, 2, false, 0)
    // Tile 31 (slot 1): no staging, no vmcnt; end barrier guards smem reuse.
    TILE(1, 0, false, -1)
#undef TILE
#undef STAGE_H1
#undef STAGE_H2
#undef ADV
#undef MFMA16

    // Epilogue: combine kf=1 partials into kf=0 waves via ring LDS.
    // Region per wave-pair (w&3): 32KB = 32 frags x 64 lanes x 16B.
    float* red = (float*)smem;
    if (w >= 4) {
        float* reg = red + (size_t)(w & 3) * 8192;
#pragma unroll
        for (int i = 0; i < 8; i++)
#pragma unroll
            for (int j = 0; j < 4; j++)
                *(f32x4*)(reg + ((i * 4 + j) * 64 + lane) * 4) = acc[i][j];
    }
    __syncthreads();
    if (w < 4) {
        float* reg = red + (size_t)w * 8192;
        float* outb = out + (size_t)b * SEQ * EMBED;
#pragma unroll
        for (int i = 0; i < 8; i++)
#pragma unroll
            for (int j = 0; j < 4; j++) {
                f32x4 o = *(const f32x4*)(reg + ((i * 4 + j) * 64 + lane) * 4);
                o += acc[i][j];
#pragma unroll
                for (int r = 0; r < 4; r++)
                    outb[(size_t)(q0 + wq + i * 16 + quad * 4 + r) * EMBED
                         + e0 + we + j * 16 + l15] = o[r];
            }
    }
}

// ---------------------------------------------------------------------------
extern "C" void kernel_launch(void* const* d_in, const int* in_sizes, int n_in,
                              void* d_out, int out_size, void* d_ws, size_t ws_size,
                              hipStream_t stream) {
    (void)in_sizes; (void)n_in; (void)out_size; (void)ws_size;
    const float* h  = (const float*)d_in[0];
    const float* Wq = (const float*)d_in[1];
    const float* bq = (const float*)d_in[2];
    const float* Wk = (const float*)d_in[3];
    const float* bk = (const float*)d_in[4];
    // d_in[5], d_in[6] (Wv, bv) are dead in the reference.
    float* out = (float*)d_out;

    char* ws = (char*)d_ws;
    u16*   Qbf  = (u16*)(ws);                                  // 1 MB
    u16*   Kbf  = (u16*)(ws + (1ull << 20));                   // 1 MB
    u16*   hT   = (u16*)(ws + (2ull << 20));                   // 16 MB
    float* invl = (float*)(ws + (18ull << 20));                // 32 KB
    u16*   WqT  = (u16*)(ws + (18ull << 20) + (128ull << 10)); // 128 KB
    u16*   WkT  = (u16*)(ws + (18ull << 20) + (256ull << 10)); // 128 KB
    u16*   Wmat = (u16*)(ws + (19ull << 20));                  // 32 MB (total ~51 MB)

    hipLaunchKernelGGL(wt_kernel, dim3(16, 2), dim3(256), 0, stream, Wq, Wk, WqT, WkT);
    hipLaunchKernelGGL(proj_kernel, dim3(512), dim3(256), 0, stream,
                       h, WqT, WkT, bq, bk, Qbf, Kbf);
    hipLaunchKernelGGL(sw_kernel, dim3(32, 4), dim3(512), 0, stream,
                       Qbf, Kbf, Wmat, invl);
    hipLaunchKernelGGL(tscale_kernel, dim3(32, 16, 4), dim3(256), 0, stream,
                       h, invl, hT);
    hipLaunchKernelGGL(out_gemm_kernel, dim3(8, 8, 4), dim3(512), 0, stream,
                       Wmat, hT, out);
}

// Round 6
// 171.840 us; speedup vs baseline: 1.0333x; 1.0333x over previous
//
#include <hip/hip_runtime.h>
#include <hip/hip_bf16.h>
#include <math.h>

#define EMBED 1024
#define HDIM  64
#define BATCH 4
#define SEQ   2048

typedef __attribute__((ext_vector_type(8))) short short8;
typedef __attribute__((ext_vector_type(4))) float f32x4;
typedef unsigned int u32;
typedef unsigned short u16;

static __device__ __forceinline__ u16 f2bf(float f) {
    union { float f; u32 u; } v; v.f = f;
    u32 r = v.u + 0x7fffu + ((v.u >> 16) & 1u);  // round-to-nearest-even
    return (u16)(r >> 16);
}

// async global->LDS, 16B per lane. LDS dest must equal uniform_base + lane*16.
static __device__ __forceinline__ void gload_lds16(const u16* g, u16* l) {
    __builtin_amdgcn_global_load_lds(
        (const __attribute__((address_space(1))) u32*)g,
        (__attribute__((address_space(3))) u32*)l, 16, 0, 0);
}

// ---------------------------------------------------------------------------
// K0: WqT[d][e] = bf16(Wq[e][d]), WkT likewise. Also zeroes lsum (8192 f32,
// one store per thread) -- must happen every iteration (ws is re-poisoned).
// grid (16,2) x 256.
// ---------------------------------------------------------------------------
__global__ __launch_bounds__(256) void wt_kernel(
    const float* __restrict__ Wq, const float* __restrict__ Wk,
    u16* __restrict__ WqT, u16* __restrict__ WkT, float* __restrict__ lsum)
{
    __shared__ float tile[64][65];
    const float* W = blockIdx.y ? Wk : Wq;
    u16* WT = blockIdx.y ? WkT : WqT;
    int e0 = blockIdx.x * 64;
    int t = threadIdx.x, c = t & 63, r4 = t >> 6;
    lsum[(blockIdx.y * 16 + blockIdx.x) * 256 + t] = 0.f;   // covers 8192
    for (int r = r4; r < 64; r += 4)
        tile[r][c] = W[(size_t)(e0 + r) * HDIM + c];   // tile[e-e0][d]
    __syncthreads();
    for (int d = r4; d < 64; d += 4)
        WT[(size_t)d * EMBED + e0 + c] = f2bf(tile[c][d]);
}

// ---------------------------------------------------------------------------
// K1: proj only (transpose removed). Q = 0.125*(h*Wq+bq), K = h*Wk+bk.
// grid 512 (B * S/16), 256 thr, 16 s-rows/block, EC=128 per iter:
// 8 iters, 8 barriers, 8 MFMA + 4 ds_read_b128 per wave per iter.
// Double-buffered LDS; h prefetched DEPTH-2, W-frags 1 iter ahead.
// ---------------------------------------------------------------------------
__global__ __launch_bounds__(256) void proj_kernel(
    const float* __restrict__ h, const u16* __restrict__ WqT, const u16* __restrict__ WkT,
    const float* __restrict__ bq, const float* __restrict__ bk,
    u16* __restrict__ Qbf, u16* __restrict__ Kbf)
{
    __shared__ u16 hs[2][16][136];   // 128 + 8 pad
    int b = blockIdx.x >> 7, s0 = (blockIdx.x & 127) * 16;
    int t = threadIdx.x, lane = t & 63, w = t >> 6;
    int l15 = lane & 15, quad = lane >> 4;
    int pj = w >> 1, nh = (w & 1) * 32;
    const float* hb = h + ((size_t)b * SEQ + s0) * EMBED;
    const u16* Wp = pj ? WkT : WqT;
    int r = t >> 4, c4 = (t & 15) * 4;   // staging: 16 rows x (16 f32x4 x 2 halves)

    f32x4 preA0 = *(const f32x4*)(hb + (size_t)r * EMBED + c4);
    f32x4 preA1 = *(const f32x4*)(hb + (size_t)r * EMBED + 64 + c4);
    f32x4 preB0 = *(const f32x4*)(hb + (size_t)r * EMBED + 128 + c4);
    f32x4 preB1 = *(const f32x4*)(hb + (size_t)r * EMBED + 192 + c4);
    f32x4 accA[2], accB[2];
    accA[0] = accA[1] = accB[0] = accB[1] = (f32x4){0.f, 0.f, 0.f, 0.f};

    const u16* Wrow0 = Wp + (size_t)(nh + l15) * EMBED;
    const u16* Wrow1 = Wp + (size_t)(nh + 16 + l15) * EMBED;

    short8 cw[8];
#pragma unroll
    for (int i = 0; i < 4; i++) {
        cw[i]     = *(const short8*)(Wrow0 + i * 32 + quad * 8);
        cw[4 + i] = *(const short8*)(Wrow1 + i * 32 + quad * 8);
    }

    for (int it = 0; it < 8; ++it) {
        int ec = it * 128, buf = it & 1;
        uint2 pk;
        pk.x = (u32)f2bf(preA0[0]) | ((u32)f2bf(preA0[1]) << 16);
        pk.y = (u32)f2bf(preA0[2]) | ((u32)f2bf(preA0[3]) << 16);
        *(uint2*)&hs[buf][r][c4] = pk;
        pk.x = (u32)f2bf(preA1[0]) | ((u32)f2bf(preA1[1]) << 16);
        pk.y = (u32)f2bf(preA1[2]) | ((u32)f2bf(preA1[3]) << 16);
        *(uint2*)&hs[buf][r][64 + c4] = pk;
        __syncthreads();

        preA0 = preB0; preA1 = preB1;
        if (it + 2 < 8) {
            preB0 = *(const f32x4*)(hb + (size_t)r * EMBED + ec + 256 + c4);
            preB1 = *(const f32x4*)(hb + (size_t)r * EMBED + ec + 320 + c4);
        }
        short8 nw[8];
#pragma unroll
        for (int i = 0; i < 8; i++) nw[i] = cw[i];
        if (it + 1 < 8) {
#pragma unroll
            for (int i = 0; i < 4; i++) {
                nw[i]     = *(const short8*)(Wrow0 + ec + 128 + i * 32 + quad * 8);
                nw[4 + i] = *(const short8*)(Wrow1 + ec + 128 + i * 32 + quad * 8);
            }
        }

        short8 a0 = *(const short8*)&hs[buf][l15][quad * 8];
        short8 a1 = *(const short8*)&hs[buf][l15][32 + quad * 8];
        short8 a2 = *(const short8*)&hs[buf][l15][64 + quad * 8];
        short8 a3 = *(const short8*)&hs[buf][l15][96 + quad * 8];
        // dependent accumulator reuses 4 apart
        accA[0] = __builtin_amdgcn_mfma_f32_16x16x32_bf16(a0, cw[0], accA[0], 0, 0, 0);
        accA[1] = __builtin_amdgcn_mfma_f32_16x16x32_bf16(a0, cw[4], accA[1], 0, 0, 0);
        accB[0] = __builtin_amdgcn_mfma_f32_16x16x32_bf16(a1, cw[1], accB[0], 0, 0, 0);
        accB[1] = __builtin_amdgcn_mfma_f32_16x16x32_bf16(a1, cw[5], accB[1], 0, 0, 0);
        accA[0] = __builtin_amdgcn_mfma_f32_16x16x32_bf16(a2, cw[2], accA[0], 0, 0, 0);
        accA[1] = __builtin_amdgcn_mfma_f32_16x16x32_bf16(a2, cw[6], accA[1], 0, 0, 0);
        accB[0] = __builtin_amdgcn_mfma_f32_16x16x32_bf16(a3, cw[3], accB[0], 0, 0, 0);
        accB[1] = __builtin_amdgcn_mfma_f32_16x16x32_bf16(a3, cw[7], accB[1], 0, 0, 0);
#pragma unroll
        for (int i = 0; i < 8; i++) cw[i] = nw[i];
    }

    const float* bias = pj ? bk : bq;
    float scale = pj ? 1.0f : 0.125f;
    u16* outp = pj ? Kbf : Qbf;
    float bv0 = bias[nh + l15], bv1 = bias[nh + 16 + l15];
#pragma unroll
    for (int rr = 0; rr < 4; rr++) {
        size_t row = (size_t)b * SEQ + s0 + quad * 4 + rr;
        outp[row * HDIM + nh + l15]      = f2bf((accA[0][rr] + accB[0][rr] + bv0) * scale);
        outp[row * HDIM + nh + 16 + l15] = f2bf((accA[1][rr] + accB[1][rr] + bv1) * scale);
    }
}

// ---------------------------------------------------------------------------
// K2 V3: coalesced-line sw at full occupancy. Block owns 64 CONTIGUOUS k x
// 512 q (q split over 4 blocks; R5 lesson: 128 blocks = half the GPU idle).
// grid (S/64, 4, B) = 512 blocks x 512 thr (16 waves/CU). Wave owns 64 q.
// Each q-row's 128B Wmat line filled by one wave (write-combining friendly).
// Column sums are PARTIAL per block -> atomicAdd into lsum (zeroed by wt;
// 8 adds/address total). tscale computes invl = rcp(lsum).
// Per 32-q iter: 16 MFMA -> 32 exp -> 8 packed uint2 stores + sum accum.
// ---------------------------------------------------------------------------
__global__ __launch_bounds__(512) void sw_kernel(
    const u16* __restrict__ Qbf, const u16* __restrict__ Kbf,
    u16* __restrict__ Wmat, float* __restrict__ lsum)
{
    int b = blockIdx.z;
    int k0 = blockIdx.x * 64;
    int t = threadIdx.x, lane = t & 63, w = t >> 6;
    int l15 = lane & 15, quad = lane >> 4;
    const u16* Qb = Qbf + (size_t)b * SEQ * HDIM;
    const u16* Kb = Kbf + (size_t)b * SEQ * HDIM;
    u16* Wb = Wmat + (size_t)b * SEQ * SEQ;

    // K fragments: 4 k-16-groups x 2 d-halves, loop-invariant.
    short8 kfr[4][2];
#pragma unroll
    for (int g = 0; g < 4; g++)
#pragma unroll
        for (int hh = 0; hh < 2; hh++)
            kfr[g][hh] = *(const short8*)(
                Kb + (size_t)(k0 + g * 16 + l15) * HDIM + hh * 32 + quad * 8);

    f32x4 lacc[4];
#pragma unroll
    for (int g = 0; g < 4; g++) lacc[g] = (f32x4){0.f, 0.f, 0.f, 0.f};

    int qs = (blockIdx.y * 8 + w) * 64;   // wave owns 64 q

#pragma unroll
    for (int half = 0; half < 2; ++half) {
        int q0 = qs + half * 32;
        short8 cf[2][2];
#pragma unroll
        for (int a = 0; a < 2; a++)
#pragma unroll
            for (int hh = 0; hh < 2; hh++)
                cf[a][hh] = *(const short8*)(
                    Qb + (size_t)(q0 + a * 16 + l15) * HDIM + hh * 32 + quad * 8);

        // A = K rows (m=k), B = Q rows (n=q):
        // acc[a][g][r] = S[q0 + a*16 + l15][k0 + g*16 + quad*4 + r]
        f32x4 acc[2][4];
#pragma unroll
        for (int a = 0; a < 2; a++)
#pragma unroll
            for (int g = 0; g < 4; g++) acc[a][g] = (f32x4){0.f, 0.f, 0.f, 0.f};
#pragma unroll
        for (int a = 0; a < 2; a++)
#pragma unroll
            for (int g = 0; g < 4; g++) {
                acc[a][g] = __builtin_amdgcn_mfma_f32_16x16x32_bf16(
                    kfr[g][0], cf[a][0], acc[a][g], 0, 0, 0);
                acc[a][g] = __builtin_amdgcn_mfma_f32_16x16x32_bf16(
                    kfr[g][1], cf[a][1], acc[a][g], 0, 0, 0);
            }
#pragma unroll
        for (int a = 0; a < 2; a++) {
            u16* wrow = Wb + (size_t)(q0 + a * 16 + l15) * SEQ + k0;
#pragma unroll
            for (int g = 0; g < 4; g++) {
                float e0 = __expf(acc[a][g][0]), e1 = __expf(acc[a][g][1]);
                float e2 = __expf(acc[a][g][2]), e3 = __expf(acc[a][g][3]);
                lacc[g][0] += e0; lacc[g][1] += e1;
                lacc[g][2] += e2; lacc[g][3] += e3;
                uint2 pk;
                pk.x = (u32)f2bf(e0) | ((u32)f2bf(e1) << 16);
                pk.y = (u32)f2bf(e2) | ((u32)f2bf(e3) << 16);
                *(uint2*)(wrow + g * 16 + quad * 4) = pk;
            }
        }
    }
    // sum over l15 (q within tile): butterfly over lane bits 0..3
#pragma unroll
    for (int m = 1; m <= 8; m <<= 1)
#pragma unroll
        for (int g = 0; g < 4; g++) {
            lacc[g][0] += __shfl_xor(lacc[g][0], m, 64);
            lacc[g][1] += __shfl_xor(lacc[g][1], m, 64);
            lacc[g][2] += __shfl_xor(lacc[g][2], m, 64);
            lacc[g][3] += __shfl_xor(lacc[g][3], m, 64);
        }
    if (l15 == 0) {
        float* lp = lsum + b * SEQ + k0 + quad * 4;
#pragma unroll
        for (int g = 0; g < 4; g++) {
            atomicAdd(lp + g * 16 + 0, lacc[g][0]);
            atomicAdd(lp + g * 16 + 1, lacc[g][1]);
            atomicAdd(lp + g * 16 + 2, lacc[g][2]);
            atomicAdd(lp + g * 16 + 3, lacc[g][3]);
        }
    }
}

// ---------------------------------------------------------------------------
// K3: transpose + scale: hT[b][e][s] = bf16( h[b][s][e] * rcp(lsum[b][s]) ).
// 64x64 fp32 LDS tile, f32x4 global loads, uint2 packed stores.
// v_rcp error ~1e-7 << bf16 rounding. grid (S/64, E/64, B) x 256.
// ---------------------------------------------------------------------------
__global__ __launch_bounds__(256) void tscale_kernel(
    const float* __restrict__ h, const float* __restrict__ lsum,
    u16* __restrict__ hT)
{
    __shared__ float tile[64][65];
    int b  = blockIdx.z;
    int s0 = blockIdx.x * 64, e0 = blockIdx.y * 64;
    int t = threadIdx.x;
    int r16 = t >> 4, c4 = (t & 15) * 4;
    const float* hb = h + (size_t)b * SEQ * EMBED;
#pragma unroll
    for (int rr = r16; rr < 64; rr += 16) {
        f32x4 v = *(const f32x4*)(hb + (size_t)(s0 + rr) * EMBED + e0 + c4);
        *(f32x4*)&tile[rr][c4] = v;
    }
    __syncthreads();
    f32x4 ls = *(const f32x4*)(lsum + b * SEQ + s0 + c4);   // 4 s-columns
    f32x4 il4;
    il4[0] = __builtin_amdgcn_rcpf(ls[0]);
    il4[1] = __builtin_amdgcn_rcpf(ls[1]);
    il4[2] = __builtin_amdgcn_rcpf(ls[2]);
    il4[3] = __builtin_amdgcn_rcpf(ls[3]);
    u16* hTb = hT + (size_t)b * EMBED * SEQ;
#pragma unroll
    for (int er = r16; er < 64; er += 16) {
        u16 p0 = f2bf(tile[c4 + 0][er] * il4[0]);
        u16 p1 = f2bf(tile[c4 + 1][er] * il4[1]);
        u16 p2 = f2bf(tile[c4 + 2][er] * il4[2]);
        u16 p3 = f2bf(tile[c4 + 3][er] * il4[3]);
        uint2 pk;
        pk.x = (u32)p0 | ((u32)p1 << 16);
        pk.y = (u32)p2 | ((u32)p3 << 16);
        *(uint2*)(hTb + (size_t)(e0 + er) * SEQ + s0 + c4) = pk;
    }
}

// ---------------------------------------------------------------------------
// K4: out[b][q][e] = sum_k Wmat[b][q][k] * hT[b][e][k]
// V5 (frozen from R5 -- it dropped below the fill floor): lockstep 2-phase
// counted-vmcnt schedule + hoisted loop-invariant addressing.
// BM=256 x BN=128, BK=64, 512 thr = 8 waves (2 kf x 2M x 2N; wave tile
// 128x64 over its 32-wide k-half; acc[8][4]). 3-slot LDS ring (144KB),
// depth-2 staging, vmcnt(6) counted, never 0 until kt=30.
// grid (8,8,4) = 256 blocks = 1/CU.
// ---------------------------------------------------------------------------
__global__ __launch_bounds__(512, 2) void out_gemm_kernel(
    const u16* __restrict__ Wmat, const u16* __restrict__ hT, float* __restrict__ out)
{
    __shared__ __align__(16) char smem[3 * 49152];   // 3 x (A 32KB + B 16KB)
    int b = blockIdx.z;
    int q0 = blockIdx.x * 256, e0 = blockIdx.y * 128;
    int t = threadIdx.x, lane = t & 63, w = t >> 6;
    int l15 = lane & 15, quad = lane >> 4;
    const u16* Wb  = Wmat + (size_t)b * SEQ * SEQ;
    const u16* hTb = hT + (size_t)b * EMBED * SEQ;
    int kf = w >> 2;                 // k-half group (0: k 0..31, 1: k 32..63)
    int wm = (w >> 1) & 1, wn = w & 1;
    int wq = wm * 128, we = wn * 64; // wave tile origin (128 x 64)

    f32x4 acc[8][4];
#pragma unroll
    for (int i = 0; i < 8; i++)
#pragma unroll
        for (int j = 0; j < 4; j++) acc[i][j] = (f32x4){0.f, 0.f, 0.f, 0.f};

    int st_rl = lane >> 3;            // row within 8-row group
    int st_pc = lane & 7;             // physical chunk at dest (= lane pattern)

    // ---- loop-invariant staging sources (advance +64 u16 per staged tile)
    const u16* gA[4];
    const u16* gB[2];
#pragma unroll
    for (int ld = 0; ld < 4; ld++) {
        int row = w * 32 + ld * 8 + st_rl;
        int cg  = st_pc ^ (row & 7);
        gA[ld] = Wb + (size_t)(q0 + row) * SEQ + cg * 8;
    }
#pragma unroll
    for (int ld = 0; ld < 2; ld++) {
        int row = w * 16 + ld * 8 + st_rl;
        int cg  = st_pc ^ (row & 7);
        gB[ld] = hTb + (size_t)(e0 + row) * SEQ + cg * 8;
    }
    // ---- loop-invariant LDS dest byte offsets within a slot
    int dA[4], dB[2];
#pragma unroll
    for (int ld = 0; ld < 4; ld++) dA[ld] = (w * 32 + ld * 8) * 128 + lane * 16;
#pragma unroll
    for (int ld = 0; ld < 2; ld++) dB[ld] = 32768 + (w * 16 + ld * 8) * 128 + lane * 16;
    // ---- loop-invariant LDS read byte offsets within a slot
    int offA[8], offB[4];
#pragma unroll
    for (int ii = 0; ii < 8; ii++) {
        int ra  = wq + ii * 16 + l15;
        int pca = (kf * 4 + quad) ^ (ra & 7);
        offA[ii] = ra * 128 + pca * 16;
    }
#pragma unroll
    for (int j = 0; j < 4; j++) {
        int rb  = we + j * 16 + l15;
        int pcb = (kf * 4 + quad) ^ (rb & 7);
        offB[j] = 32768 + rb * 128 + pcb * 16;
    }

#define STAGE_H1(si)                                                           \
    {                                                                          \
        gload_lds16(gA[0], (u16*)(smem + (si) * 49152 + dA[0]));               \
        gload_lds16(gA[1], (u16*)(smem + (si) * 49152 + dA[1]));               \
        gload_lds16(gB[0], (u16*)(smem + (si) * 49152 + dB[0]));               \
    }
#define STAGE_H2(si)                                                           \
    {                                                                          \
        gload_lds16(gA[2], (u16*)(smem + (si) * 49152 + dA[2]));               \
        gload_lds16(gA[3], (u16*)(smem + (si) * 49152 + dA[3]));               \
        gload_lds16(gB[1], (u16*)(smem + (si) * 49152 + dB[1]));               \
    }
#define ADV()                                                                  \
    {                                                                          \
        gA[0] += 64; gA[1] += 64; gA[2] += 64; gA[3] += 64;                    \
        gB[0] += 64; gB[1] += 64;                                              \
    }

#define MFMA16(i0)                                                             \
    {                                                                          \
        _Pragma("unroll")                                                      \
        for (int ii = 0; ii < 4; ii++)                                         \
            _Pragma("unroll")                                                  \
            for (int j = 0; j < 4; j++)                                        \
                acc[(i0) + ii][j] = __builtin_amdgcn_mfma_f32_16x16x32_bf16(   \
                    af[ii], bfr[j], acc[(i0) + ii][j], 0, 0, 0);               \
    }

    // TILE body: lockstep 2-phase, slot si (literal), staging into si2.
#define TILE(si, si2, DO_STAGE, VMC)                                           \
    {                                                                          \
        const char* Sb = smem + (si) * 49152;                                  \
        short8 af[4], bfr[4];                                                  \
        /* phase 0 */                                                          \
        _Pragma("unroll")                                                      \
        for (int ii = 0; ii < 4; ii++)                                         \
            af[ii] = *(const short8*)(Sb + offA[ii]);                          \
        _Pragma("unroll")                                                      \
        for (int j = 0; j < 4; j++)                                            \
            bfr[j] = *(const short8*)(Sb + offB[j]);                           \
        if (DO_STAGE) STAGE_H1(si2)                                            \
        __builtin_amdgcn_s_barrier();                                          \
        asm volatile("s_waitcnt lgkmcnt(0)" ::: "memory");                     \
        __builtin_amdgcn_sched_barrier(0);                                     \
        __builtin_amdgcn_s_setprio(1);                                         \
        MFMA16(0)                                                              \
        __builtin_amdgcn_s_setprio(0);                                         \
        __builtin_amdgcn_s_barrier();                                          \
        /* phase 1 */                                                          \
        _Pragma("unroll")                                                      \
        for (int ii = 0; ii < 4; ii++)                                         \
            af[ii] = *(const short8*)(Sb + offA[4 + ii]);                      \
        if (DO_STAGE) { STAGE_H2(si2) ADV() }                                  \
        __builtin_amdgcn_s_barrier();                                          \
        asm volatile("s_waitcnt lgkmcnt(0)" ::: "memory");                     \
        __builtin_amdgcn_sched_barrier(0);                                     \
        __builtin_amdgcn_s_setprio(1);                                         \
        MFMA16(4)                                                              \
        __builtin_amdgcn_s_setprio(0);                                         \
        if ((VMC) == 6) { asm volatile("s_waitcnt vmcnt(6)" ::: "memory"); }   \
        else if ((VMC) == 0) { asm volatile("s_waitcnt vmcnt(0)" ::: "memory"); } \
        __builtin_amdgcn_s_barrier();                                          \
    }

    // Prologue: stage tiles 0 (slot 0) and 1 (slot 1).
    STAGE_H1(0) STAGE_H2(0) ADV()
    STAGE_H1(1) STAGE_H2(1) ADV()
    asm volatile("s_waitcnt vmcnt(6)" ::: "memory");   // own tile-0 loads done
    __builtin_amdgcn_s_barrier();                      // published to all

    // Tiles 0..29: unrolled x3, staging tiles 2..31, vmcnt(6) each.
    for (int g = 0; g < 10; ++g) {
        TILE(0, 2, true, 6)
        TILE(1, 0, true, 6)
        TILE(2, 1, true, 6)
    }
    // Tile 30 (slot 0): no staging; drain remaining (tile 31's 6 loads).
    TILE(0, 2, false, 0)
    // Tile 31 (slot 1): no staging, no vmcnt; end barrier guards smem reuse.
    TILE(1, 0, false, -1)
#undef TILE
#undef STAGE_H1
#undef STAGE_H2
#undef ADV
#undef MFMA16

    // Epilogue: combine kf=1 partials into kf=0 waves via ring LDS.
    // Region per wave-pair (w&3): 32KB = 32 frags x 64 lanes x 16B.
    float* red = (float*)smem;
    if (w >= 4) {
        float* reg = red + (size_t)(w & 3) * 8192;
#pragma unroll
        for (int i = 0; i < 8; i++)
#pragma unroll
            for (int j = 0; j < 4; j++)
                *(f32x4*)(reg + ((i * 4 + j) * 64 + lane) * 4) = acc[i][j];
    }
    __syncthreads();
    if (w < 4) {
        float* reg = red + (size_t)w * 8192;
        float* outb = out + (size_t)b * SEQ * EMBED;
#pragma unroll
        for (int i = 0; i < 8; i++)
#pragma unroll
            for (int j = 0; j < 4; j++) {
                f32x4 o = *(const f32x4*)(reg + ((i * 4 + j) * 64 + lane) * 4);
                o += acc[i][j];
#pragma unroll
                for (int r = 0; r < 4; r++)
                    outb[(size_t)(q0 + wq + i * 16 + quad * 4 + r) * EMBED
                         + e0 + we + j * 16 + l15] = o[r];
            }
    }
}

// ---------------------------------------------------------------------------
extern "C" void kernel_launch(void* const* d_in, const int* in_sizes, int n_in,
                              void* d_out, int out_size, void* d_ws, size_t ws_size,
                              hipStream_t stream) {
    (void)in_sizes; (void)n_in; (void)out_size; (void)ws_size;
    const float* h  = (const float*)d_in[0];
    const float* Wq = (const float*)d_in[1];
    const float* bq = (const float*)d_in[2];
    const float* Wk = (const float*)d_in[3];
    const float* bk = (const float*)d_in[4];
    // d_in[5], d_in[6] (Wv, bv) are dead in the reference.
    float* out = (float*)d_out;

    char* ws = (char*)d_ws;
    u16*   Qbf  = (u16*)(ws);                                  // 1 MB
    u16*   Kbf  = (u16*)(ws + (1ull << 20));                   // 1 MB
    u16*   hT   = (u16*)(ws + (2ull << 20));                   // 16 MB
    float* lsum = (float*)(ws + (18ull << 20));                // 32 KB
    u16*   WqT  = (u16*)(ws + (18ull << 20) + (128ull << 10)); // 128 KB
    u16*   WkT  = (u16*)(ws + (18ull << 20) + (256ull << 10)); // 128 KB
    u16*   Wmat = (u16*)(ws + (19ull << 20));                  // 32 MB (total ~51 MB)

    hipLaunchKernelGGL(wt_kernel, dim3(16, 2), dim3(256), 0, stream,
                       Wq, Wk, WqT, WkT, lsum);
    hipLaunchKernelGGL(proj_kernel, dim3(512), dim3(256), 0, stream,
                       h, WqT, WkT, bq, bk, Qbf, Kbf);
    hipLaunchKernelGGL(sw_kernel, dim3(32, 4, 4), dim3(512), 0, stream,
                       Qbf, Kbf, Wmat, lsum);
    hipLaunchKernelGGL(tscale_kernel, dim3(32, 16, 4), dim3(256), 0, stream,
                       h, lsum, hT);
    hipLaunchKernelGGL(out_gemm_kernel, dim3(8, 8, 4), dim3(512), 0, stream,
                       Wmat, hT, out);
}